// Round 1
// baseline (715.327 us; speedup 1.0000x reference)
//
#include <hip/hip_runtime.h>
#include <math.h>

// FlashDiffAttention on MI355X (gfx950).
// B=2 S=2048 H2=16 (H=8 diff heads) D=128. fp32 in/out, bf16 MFMA compute.
// Block: 256 thr = 4 waves; each wave owns 16 query rows; block owns 64.
// Key loop: BN=32 keys/tile; both attentions share V12 (256-wide) tiles.

#define S_LEN 2048
#define H2 16
#define DH 128
#define BM 64
#define BN 32

typedef __attribute__((ext_vector_type(8))) short short8;
typedef __attribute__((ext_vector_type(4))) float f32x4;

__device__ __forceinline__ short f2bf(float f) {
    unsigned u = __builtin_bit_cast(unsigned, f);
    u += 0x7fffu + ((u >> 16) & 1u);
    return (short)(u >> 16);
}

// scale * log2(e): scores computed directly in log2 domain
#define QSCALE (1.44269504088896f * 0.0883883476483184f)
#define LAMBDA_INIT 0.783605766532f
#define NEG_BIG (-3.0e38f)

__global__ __launch_bounds__(256, 2)
void fda_kernel(const float* __restrict__ q, const float* __restrict__ k,
                const float* __restrict__ v,
                const float* __restrict__ lq1, const float* __restrict__ lk1,
                const float* __restrict__ lq2, const float* __restrict__ lk2,
                float* __restrict__ out) {
    __shared__ short sK1[BN][136];       // keys x d, padded (+8) for banks
    __shared__ short sK2[BN][136];
    __shared__ short sVt[256][40];       // vdim x keys (transposed), padded
    __shared__ short sP[4][2][16][40];   // per-wave P scratch, 2 attns

    const int tid  = threadIdx.x;
    const int w    = tid >> 6;
    const int lane = tid & 63;
    const int mi   = lane & 15;
    const int quad = lane >> 4;

    const int bh = blockIdx.x & 15;
    const int qt = 31 - (blockIdx.x >> 4);     // heavy q-tiles dispatched first
    const int b  = bh >> 3;
    const int h  = bh & 7;
    const int qbase = qt * BM;

    // ---- lambda_full (uniform): two 128-dots via wave reduce ----
    float d1 = lq1[lane] * lk1[lane] + lq1[lane + 64] * lk1[lane + 64];
    float d2 = lq2[lane] * lk2[lane] + lq2[lane + 64] * lk2[lane + 64];
    #pragma unroll
    for (int off = 32; off; off >>= 1) {
        d1 += __shfl_xor(d1, off);
        d2 += __shfl_xor(d2, off);
    }
    const float lambda_full = expf(d1) - expf(d2) + LAMBDA_INIT;

    // ---- load Q fragments (A-layout: row=mi, k = db*32 + quad*8 + j) ----
    short8 q1f[4], q2f[4];
    {
        const int qrow = qbase + w * 16 + mi;
        const float* qg1 = q + (((size_t)b * S_LEN + qrow) * H2 + 2 * h) * DH;
        const float* qg2 = qg1 + DH;
        #pragma unroll
        for (int db = 0; db < 4; ++db) {
            const float* p1 = qg1 + db * 32 + quad * 8;
            float4 xa = *(const float4*)p1;
            float4 xb = *(const float4*)(p1 + 4);
            short8 f;
            f[0] = f2bf(xa.x * QSCALE); f[1] = f2bf(xa.y * QSCALE);
            f[2] = f2bf(xa.z * QSCALE); f[3] = f2bf(xa.w * QSCALE);
            f[4] = f2bf(xb.x * QSCALE); f[5] = f2bf(xb.y * QSCALE);
            f[6] = f2bf(xb.z * QSCALE); f[7] = f2bf(xb.w * QSCALE);
            q1f[db] = f;
            const float* p2 = qg2 + db * 32 + quad * 8;
            xa = *(const float4*)p2;
            xb = *(const float4*)(p2 + 4);
            f[0] = f2bf(xa.x * QSCALE); f[1] = f2bf(xa.y * QSCALE);
            f[2] = f2bf(xa.z * QSCALE); f[3] = f2bf(xa.w * QSCALE);
            f[4] = f2bf(xb.x * QSCALE); f[5] = f2bf(xb.y * QSCALE);
            f[6] = f2bf(xb.z * QSCALE); f[7] = f2bf(xb.w * QSCALE);
            q2f[db] = f;
        }
    }

    // ---- state ----
    float m1[4], l1[4], m2[4], l2[4];
    #pragma unroll
    for (int r = 0; r < 4; ++r) { m1[r] = -1e30f; m2[r] = -1e30f; l1[r] = 0.f; l2[r] = 0.f; }
    f32x4 O1[16], O2[16];
    #pragma unroll
    for (int i = 0; i < 16; ++i) { O1[i] = (f32x4){0.f,0.f,0.f,0.f}; O2[i] = (f32x4){0.f,0.f,0.f,0.f}; }

    const int nt = 2 * qt + 2;
    for (int t = 0; t < nt; ++t) {
        const int t0 = t * BN;
        __syncthreads();

        // ---- stage K1,K2 (32x128 fp32 -> bf16 LDS) ----
        #pragma unroll
        for (int cc = 0; cc < 2; ++cc) {
            const int c   = tid + cc * 256;       // 512 chunks of 8 d-values
            const int row = c >> 4;
            const int d0  = (c & 15) * 8;
            const float* gk = k + (((size_t)b * S_LEN + t0 + row) * H2 + 2 * h) * DH + d0;
            float4 a0 = *(const float4*)gk;
            float4 a1 = *(const float4*)(gk + 4);
            short8 sv;
            sv[0]=f2bf(a0.x); sv[1]=f2bf(a0.y); sv[2]=f2bf(a0.z); sv[3]=f2bf(a0.w);
            sv[4]=f2bf(a1.x); sv[5]=f2bf(a1.y); sv[6]=f2bf(a1.z); sv[7]=f2bf(a1.w);
            *(short8*)&sK1[row][d0] = sv;
            const float* gk2 = gk + DH;
            a0 = *(const float4*)gk2;
            a1 = *(const float4*)(gk2 + 4);
            sv[0]=f2bf(a0.x); sv[1]=f2bf(a0.y); sv[2]=f2bf(a0.z); sv[3]=f2bf(a0.w);
            sv[4]=f2bf(a1.x); sv[5]=f2bf(a1.y); sv[6]=f2bf(a1.z); sv[7]=f2bf(a1.w);
            *(short8*)&sK2[row][d0] = sv;
        }

        // ---- stage V12 transposed (32 keys x 256 n) ----
        #pragma unroll
        for (int j = 0; j < 8; ++j) {
            const int e4  = j * 256 + tid;        // float4 index in tile
            const int key = e4 >> 6;              // 64 float4 per key-row
            const int n0  = (e4 & 63) * 4;
            const float* gv = v + (((size_t)b * S_LEN + t0 + key) * H2 + 2 * h) * DH + n0;
            float4 a = *(const float4*)gv;
            sVt[n0    ][key] = f2bf(a.x);
            sVt[n0 + 1][key] = f2bf(a.y);
            sVt[n0 + 2][key] = f2bf(a.z);
            sVt[n0 + 3][key] = f2bf(a.w);
        }
        __syncthreads();

        // ---- QK^T: S tiles (C-layout: row=quad*4+reg query, col=mi key) ----
        f32x4 s1a = (f32x4){0.f,0.f,0.f,0.f}, s1b = s1a, s2a = s1a, s2b = s1a;
        #pragma unroll
        for (int db = 0; db < 4; ++db) {
            short8 kb;
            kb = *(const short8*)&sK1[mi][db * 32 + quad * 8];
            s1a = __builtin_amdgcn_mfma_f32_16x16x32_bf16(q1f[db], kb, s1a, 0, 0, 0);
            kb = *(const short8*)&sK1[16 + mi][db * 32 + quad * 8];
            s1b = __builtin_amdgcn_mfma_f32_16x16x32_bf16(q1f[db], kb, s1b, 0, 0, 0);
            kb = *(const short8*)&sK2[mi][db * 32 + quad * 8];
            s2a = __builtin_amdgcn_mfma_f32_16x16x32_bf16(q2f[db], kb, s2a, 0, 0, 0);
            kb = *(const short8*)&sK2[16 + mi][db * 32 + quad * 8];
            s2b = __builtin_amdgcn_mfma_f32_16x16x32_bf16(q2f[db], kb, s2b, 0, 0, 0);
        }

        // ---- causal mask (only near/diagonal tiles) ----
        if (t0 + 31 > qbase + w * 16) {
            #pragma unroll
            for (int r = 0; r < 4; ++r) {
                const int qr = qbase + w * 16 + quad * 4 + r;
                if (t0 + mi      > qr) { s1a[r] = NEG_BIG; s2a[r] = NEG_BIG; }
                if (t0 + 16 + mi > qr) { s1b[r] = NEG_BIG; s2b[r] = NEG_BIG; }
            }
        }

        // ---- online softmax attn1 ----
        float al1[4], al2[4];
        #pragma unroll
        for (int r = 0; r < 4; ++r) {
            float mx = fmaxf(s1a[r], s1b[r]);
            mx = fmaxf(mx, __shfl_xor(mx, 1));
            mx = fmaxf(mx, __shfl_xor(mx, 2));
            mx = fmaxf(mx, __shfl_xor(mx, 4));
            mx = fmaxf(mx, __shfl_xor(mx, 8));
            const float mn = fmaxf(m1[r], mx);
            al1[r] = exp2f(m1[r] - mn);
            const float pa = exp2f(s1a[r] - mn);
            const float pb = exp2f(s1b[r] - mn);
            float rs = pa + pb;
            rs += __shfl_xor(rs, 1); rs += __shfl_xor(rs, 2);
            rs += __shfl_xor(rs, 4); rs += __shfl_xor(rs, 8);
            l1[r] = l1[r] * al1[r] + rs;
            m1[r] = mn;
            sP[w][0][quad * 4 + r][mi]      = f2bf(pa);
            sP[w][0][quad * 4 + r][mi + 16] = f2bf(pb);
        }
        // ---- online softmax attn2 ----
        #pragma unroll
        for (int r = 0; r < 4; ++r) {
            float mx = fmaxf(s2a[r], s2b[r]);
            mx = fmaxf(mx, __shfl_xor(mx, 1));
            mx = fmaxf(mx, __shfl_xor(mx, 2));
            mx = fmaxf(mx, __shfl_xor(mx, 4));
            mx = fmaxf(mx, __shfl_xor(mx, 8));
            const float mn = fmaxf(m2[r], mx);
            al2[r] = exp2f(m2[r] - mn);
            const float pa = exp2f(s2a[r] - mn);
            const float pb = exp2f(s2b[r] - mn);
            float rs = pa + pb;
            rs += __shfl_xor(rs, 1); rs += __shfl_xor(rs, 2);
            rs += __shfl_xor(rs, 4); rs += __shfl_xor(rs, 8);
            l2[r] = l2[r] * al2[r] + rs;
            m2[r] = mn;
            sP[w][1][quad * 4 + r][mi]      = f2bf(pa);
            sP[w][1][quad * 4 + r][mi + 16] = f2bf(pb);
        }

        // ---- rescale accumulators ----
        #pragma unroll
        for (int nb = 0; nb < 16; ++nb) {
            #pragma unroll
            for (int r = 0; r < 4; ++r) { O1[nb][r] *= al1[r]; O2[nb][r] *= al2[r]; }
        }

        // ---- PV: A from sP (A-layout), B from sVt ----
        const short8 a1 = *(const short8*)&sP[w][0][mi][quad * 8];
        const short8 a2 = *(const short8*)&sP[w][1][mi][quad * 8];
        #pragma unroll
        for (int nb = 0; nb < 16; ++nb) {
            const short8 bv = *(const short8*)&sVt[nb * 16 + mi][quad * 8];
            O1[nb] = __builtin_amdgcn_mfma_f32_16x16x32_bf16(a1, bv, O1[nb], 0, 0, 0);
            O2[nb] = __builtin_amdgcn_mfma_f32_16x16x32_bf16(a2, bv, O2[nb], 0, 0, 0);
        }
    }

    // ---- epilogue: combine, RMSNorm over 256, store ----
    float il1[4], il2[4], ss[4] = {0.f, 0.f, 0.f, 0.f};
    #pragma unroll
    for (int r = 0; r < 4; ++r) {
        il1[r] = 1.0f / l1[r];
        il2[r] = lambda_full / l2[r];
    }
    #pragma unroll
    for (int nb = 0; nb < 16; ++nb) {
        #pragma unroll
        for (int r = 0; r < 4; ++r) {
            const float c = O1[nb][r] * il1[r] - O2[nb][r] * il2[r];
            O1[nb][r] = c;
            ss[r] += c * c;
        }
    }
    #pragma unroll
    for (int r = 0; r < 4; ++r) {
        float s = ss[r];
        s += __shfl_xor(s, 1); s += __shfl_xor(s, 2);
        s += __shfl_xor(s, 4); s += __shfl_xor(s, 8);
        ss[r] = rsqrtf(s * (1.0f / 256.0f) + 1e-5f) * (1.0f - LAMBDA_INIT);
    }
    #pragma unroll
    for (int r = 0; r < 4; ++r) {
        const int rowg = qbase + w * 16 + quad * 4 + r;
        float* ob = out + (((size_t)b * S_LEN + rowg) * H2 + 2 * h) * DH + mi;
        #pragma unroll
        for (int nb = 0; nb < 16; ++nb) ob[nb * 16] = O1[nb][r] * ss[r];
    }
}

extern "C" void kernel_launch(void* const* d_in, const int* in_sizes, int n_in,
                              void* d_out, int out_size, void* d_ws, size_t ws_size,
                              hipStream_t stream) {
    (void)in_sizes; (void)n_in; (void)out_size; (void)d_ws; (void)ws_size;
    const float* q   = (const float*)d_in[0];
    const float* k   = (const float*)d_in[1];
    const float* v   = (const float*)d_in[2];
    const float* lq1 = (const float*)d_in[3];
    const float* lk1 = (const float*)d_in[4];
    const float* lq2 = (const float*)d_in[5];
    const float* lk2 = (const float*)d_in[6];
    float* out = (float*)d_out;
    // 512 blocks = 32 q-tiles (heavy-first) x 16 (b,h)
    fda_kernel<<<dim3(512), dim3(256), 0, stream>>>(q, k, v, lq1, lk1, lq2, lk2, out);
}

// Round 2
// 390.360 us; speedup vs baseline: 1.8325x; 1.8325x over previous
//
#include <hip/hip_runtime.h>
#include <math.h>

// FlashDiffAttention on MI355X (gfx950). Round 2.
// B=2 S=2048 H2=16 (H=8 diff heads) D=128. fp32 in/out, bf16 MFMA compute.
// Block: 256 thr = 4 waves = (2 row-groups x 2 n-halves). BM=32 rows/block.
// Balance: block p handles q-tiles p and 63-p sequentially -> 65 key-tiles
// for EVERY block (uniform). Grid 512 = 2 blocks/CU steady.
// V transposed in LDS with chunk-rotation swizzle -> 2-way (free) banks.

#define S_LEN 2048
#define ROWSTR 2048       // H2*DH floats per (b,s) row
#define BN 32

typedef __attribute__((ext_vector_type(8))) short short8;
typedef __attribute__((ext_vector_type(4))) float f32x4;

__device__ __forceinline__ short f2bf(float f) {
    unsigned u = __builtin_bit_cast(unsigned, f);
    u += 0x7fffu + ((u >> 16) & 1u);
    return (short)(u >> 16);
}

#define QSCALE (1.44269504088896f * 0.0883883476483184f)  // log2(e)/sqrt(128)
#define LAMBDA_INIT 0.783605766532f
#define NEG_BIG (-3.0e38f)

__global__ __launch_bounds__(256, 2)
void fda_kernel(const float* __restrict__ q, const float* __restrict__ k,
                const float* __restrict__ v,
                const float* __restrict__ lq1, const float* __restrict__ lk1,
                const float* __restrict__ lq2, const float* __restrict__ lk2,
                float* __restrict__ out) {
    __shared__ short sK1[BN][136];      // 32 keys x 128 d (+8 pad): 2-way banks
    __shared__ short sK2[BN][136];
    __shared__ short sVt[256][40];      // n x keys, chunk-swizzled: 2-way banks
    __shared__ short sP[4][2][16][40];  // per-wave P scratch, 2 attns
    __shared__ float sRed[2][2][16];    // RMSNorm cross-n-half partials

    const int tid  = threadIdx.x;
    const int w    = tid >> 6;
    const int lane = tid & 63;
    const int mi   = lane & 15;
    const int quad = lane >> 4;
    const int rg   = w & 1;             // row-group (16 rows each)
    const int u    = w >> 1;            // n-half (128 wide each)

    const int bh  = blockIdx.x & 15;
    const int pid = blockIdx.x >> 4;    // pair id 0..31
    const int b   = bh >> 3;
    const int h   = bh & 7;

    const float* qg = q + (size_t)b * S_LEN * ROWSTR + h * 256;
    const float* kg = k + (size_t)b * S_LEN * ROWSTR + h * 256;
    const float* vg = v + (size_t)b * S_LEN * ROWSTR + h * 256;

    // ---- lambda_full (uniform) ----
    float d1 = lq1[lane] * lk1[lane] + lq1[lane + 64] * lk1[lane + 64];
    float d2 = lq2[lane] * lk2[lane] + lq2[lane + 64] * lk2[lane + 64];
    #pragma unroll
    for (int off = 32; off; off >>= 1) {
        d1 += __shfl_xor(d1, off);
        d2 += __shfl_xor(d2, off);
    }
    const float lambda_full = expf(d1) - expf(d2) + LAMBDA_INIT;

    const int rhoV = (tid >> 3) & 3;    // V staging chunk rotation for this lane

    for (int ph = 0; ph < 2; ++ph) {
        const int qt = ph ? (63 - pid) : pid;      // q-tile of 32 rows
        const int qrow0 = qt * 32 + rg * 16;       // this wave's row base

        // ---- load Q fragments (A-layout: row=mi, k=db*32+quad*8+j) ----
        short8 q1f[4], q2f[4];
        {
            const float* g1 = qg + (size_t)(qrow0 + mi) * ROWSTR;
            #pragma unroll
            for (int db = 0; db < 4; ++db) {
                const float* p1 = g1 + db * 32 + quad * 8;
                float4 xa = *(const float4*)p1;
                float4 xb = *(const float4*)(p1 + 4);
                short8 f;
                f[0] = f2bf(xa.x * QSCALE); f[1] = f2bf(xa.y * QSCALE);
                f[2] = f2bf(xa.z * QSCALE); f[3] = f2bf(xa.w * QSCALE);
                f[4] = f2bf(xb.x * QSCALE); f[5] = f2bf(xb.y * QSCALE);
                f[6] = f2bf(xb.z * QSCALE); f[7] = f2bf(xb.w * QSCALE);
                q1f[db] = f;
                const float* p2 = p1 + 128;
                xa = *(const float4*)p2;
                xb = *(const float4*)(p2 + 4);
                f[0] = f2bf(xa.x * QSCALE); f[1] = f2bf(xa.y * QSCALE);
                f[2] = f2bf(xa.z * QSCALE); f[3] = f2bf(xa.w * QSCALE);
                f[4] = f2bf(xb.x * QSCALE); f[5] = f2bf(xb.y * QSCALE);
                f[6] = f2bf(xb.z * QSCALE); f[7] = f2bf(xb.w * QSCALE);
                q2f[db] = f;
            }
        }

        // ---- per-phase state ----
        float m1[4], l1[4], m2[4], l2[4];
        #pragma unroll
        for (int r = 0; r < 4; ++r) { m1[r] = -1e30f; m2[r] = -1e30f; l1[r] = 0.f; l2[r] = 0.f; }
        f32x4 O1[8], O2[8];
        #pragma unroll
        for (int i = 0; i < 8; ++i) { O1[i] = (f32x4){0.f,0.f,0.f,0.f}; O2[i] = (f32x4){0.f,0.f,0.f,0.f}; }

        for (int t = 0; t <= qt; ++t) {
            const int t0 = t * BN;
            __syncthreads();

            // ---- stage K1,K2: 32 keys x 128 d, fp32 -> bf16 LDS ----
            #pragma unroll
            for (int cc = 0; cc < 2; ++cc) {
                const int c   = tid + cc * 256;
                const int row = c >> 4;
                const int d0  = (c & 15) * 8;
                const float* gk = kg + (size_t)(t0 + row) * ROWSTR + d0;
                float4 a0 = *(const float4*)gk;
                float4 a1 = *(const float4*)(gk + 4);
                short8 sv;
                sv[0]=f2bf(a0.x); sv[1]=f2bf(a0.y); sv[2]=f2bf(a0.z); sv[3]=f2bf(a0.w);
                sv[4]=f2bf(a1.x); sv[5]=f2bf(a1.y); sv[6]=f2bf(a1.z); sv[7]=f2bf(a1.w);
                *(short8*)&sK1[row][d0] = sv;
                const float* gk2 = gk + 128;
                a0 = *(const float4*)gk2;
                a1 = *(const float4*)(gk2 + 4);
                sv[0]=f2bf(a0.x); sv[1]=f2bf(a0.y); sv[2]=f2bf(a0.z); sv[3]=f2bf(a0.w);
                sv[4]=f2bf(a1.x); sv[5]=f2bf(a1.y); sv[6]=f2bf(a1.z); sv[7]=f2bf(a1.w);
                *(short8*)&sK2[row][d0] = sv;
            }

            // ---- stage V transposed: thread owns column n=tid, 32 keys ----
            // loads row-uniform (fully coalesced); writes b128 with chunk
            // rotation (c ^ rhoV) -> 2-way banks (free)
            {
                const float* gv = vg + (size_t)t0 * ROWSTR + tid;
                #pragma unroll
                for (int c = 0; c < 4; ++c) {
                    float vv[8];
                    #pragma unroll
                    for (int j = 0; j < 8; ++j)
                        vv[j] = gv[(size_t)(c * 8 + j) * ROWSTR];
                    short8 sv;
                    #pragma unroll
                    for (int j = 0; j < 8; ++j) sv[j] = f2bf(vv[j]);
                    *(short8*)&sVt[tid][((c ^ rhoV) & 3) * 8] = sv;
                }
            }
            __syncthreads();

            // ---- QK^T (C-layout: row=quad*4+r, col=mi key) ----
            f32x4 s1a = (f32x4){0.f,0.f,0.f,0.f}, s1b = s1a, s2a = s1a, s2b = s1a;
            #pragma unroll
            for (int db = 0; db < 4; ++db) {
                short8 kb;
                kb = *(const short8*)&sK1[mi][db * 32 + quad * 8];
                s1a = __builtin_amdgcn_mfma_f32_16x16x32_bf16(q1f[db], kb, s1a, 0, 0, 0);
                kb = *(const short8*)&sK1[16 + mi][db * 32 + quad * 8];
                s1b = __builtin_amdgcn_mfma_f32_16x16x32_bf16(q1f[db], kb, s1b, 0, 0, 0);
                kb = *(const short8*)&sK2[mi][db * 32 + quad * 8];
                s2a = __builtin_amdgcn_mfma_f32_16x16x32_bf16(q2f[db], kb, s2a, 0, 0, 0);
                kb = *(const short8*)&sK2[16 + mi][db * 32 + quad * 8];
                s2b = __builtin_amdgcn_mfma_f32_16x16x32_bf16(q2f[db], kb, s2b, 0, 0, 0);
            }

            // ---- causal mask: only the diagonal tile needs it ----
            if (t == qt) {
                #pragma unroll
                for (int r = 0; r < 4; ++r) {
                    const int qr = qrow0 + quad * 4 + r;
                    if (t0 + mi      > qr) { s1a[r] = NEG_BIG; s2a[r] = NEG_BIG; }
                    if (t0 + 16 + mi > qr) { s1b[r] = NEG_BIG; s2b[r] = NEG_BIG; }
                }
            }

            // ---- online softmax (log2 domain), both attns ----
            float al1[4], al2[4];
            #pragma unroll
            for (int r = 0; r < 4; ++r) {
                float mx = fmaxf(s1a[r], s1b[r]);
                mx = fmaxf(mx, __shfl_xor(mx, 1));
                mx = fmaxf(mx, __shfl_xor(mx, 2));
                mx = fmaxf(mx, __shfl_xor(mx, 4));
                mx = fmaxf(mx, __shfl_xor(mx, 8));
                const float mn = fmaxf(m1[r], mx);
                al1[r] = exp2f(m1[r] - mn);
                const float pa = exp2f(s1a[r] - mn);
                const float pb = exp2f(s1b[r] - mn);
                float rs = pa + pb;
                rs += __shfl_xor(rs, 1); rs += __shfl_xor(rs, 2);
                rs += __shfl_xor(rs, 4); rs += __shfl_xor(rs, 8);
                l1[r] = l1[r] * al1[r] + rs;
                m1[r] = mn;
                sP[w][0][quad * 4 + r][mi]      = f2bf(pa);
                sP[w][0][quad * 4 + r][mi + 16] = f2bf(pb);
            }
            #pragma unroll
            for (int r = 0; r < 4; ++r) {
                float mx = fmaxf(s2a[r], s2b[r]);
                mx = fmaxf(mx, __shfl_xor(mx, 1));
                mx = fmaxf(mx, __shfl_xor(mx, 2));
                mx = fmaxf(mx, __shfl_xor(mx, 4));
                mx = fmaxf(mx, __shfl_xor(mx, 8));
                const float mn = fmaxf(m2[r], mx);
                al2[r] = exp2f(m2[r] - mn);
                const float pa = exp2f(s2a[r] - mn);
                const float pb = exp2f(s2b[r] - mn);
                float rs = pa + pb;
                rs += __shfl_xor(rs, 1); rs += __shfl_xor(rs, 2);
                rs += __shfl_xor(rs, 4); rs += __shfl_xor(rs, 8);
                l2[r] = l2[r] * al2[r] + rs;
                m2[r] = mn;
                sP[w][1][quad * 4 + r][mi]      = f2bf(pa);
                sP[w][1][quad * 4 + r][mi + 16] = f2bf(pb);
            }

            // ---- rescale accumulators ----
            #pragma unroll
            for (int nb = 0; nb < 8; ++nb) {
                #pragma unroll
                for (int r = 0; r < 4; ++r) { O1[nb][r] *= al1[r]; O2[nb][r] *= al2[r]; }
            }

            // ---- PV over this wave's 128-wide n-half ----
            const short8 a1 = *(const short8*)&sP[w][0][mi][quad * 8];
            const short8 a2 = *(const short8*)&sP[w][1][mi][quad * 8];
            #pragma unroll
            for (int nb = 0; nb < 8; ++nb) {
                const int n   = u * 128 + nb * 16 + mi;
                const int rho = ((n >> 3) & 3);
                const short8 bv = *(const short8*)&sVt[n][((quad ^ rho) & 3) * 8];
                O1[nb] = __builtin_amdgcn_mfma_f32_16x16x32_bf16(a1, bv, O1[nb], 0, 0, 0);
                O2[nb] = __builtin_amdgcn_mfma_f32_16x16x32_bf16(a2, bv, O2[nb], 0, 0, 0);
            }
        }

        // ---- epilogue: combine, RMSNorm over 256 (cross-n-half), store ----
        float il1[4], il2[4], ss4[4] = {0.f, 0.f, 0.f, 0.f};
        #pragma unroll
        for (int r = 0; r < 4; ++r) {
            il1[r] = 1.0f / l1[r];
            il2[r] = lambda_full / l2[r];
        }
        #pragma unroll
        for (int nb = 0; nb < 8; ++nb) {
            #pragma unroll
            for (int r = 0; r < 4; ++r) {
                const float c = O1[nb][r] * il1[r] - O2[nb][r] * il2[r];
                O1[nb][r] = c;
                ss4[r] += c * c;
            }
        }
        #pragma unroll
        for (int r = 0; r < 4; ++r) {
            float s = ss4[r];
            s += __shfl_xor(s, 1); s += __shfl_xor(s, 2);
            s += __shfl_xor(s, 4); s += __shfl_xor(s, 8);
            ss4[r] = s;                 // this wave's 128-wide partial
        }
        if (mi == 0) {
            #pragma unroll
            for (int r = 0; r < 4; ++r) sRed[rg][u][quad * 4 + r] = ss4[r];
        }
        __syncthreads();
        #pragma unroll
        for (int r = 0; r < 4; ++r) {
            const float tot = ss4[r] + sRed[rg][u ^ 1][quad * 4 + r];
            ss4[r] = rsqrtf(tot * (1.0f / 256.0f) + 1e-5f) * (1.0f - LAMBDA_INIT);
        }
        #pragma unroll
        for (int r = 0; r < 4; ++r) {
            const int rowg = qrow0 + quad * 4 + r;
            float* ob = out + (size_t)(b * S_LEN + rowg) * ROWSTR + h * 256 + u * 128 + mi;
            #pragma unroll
            for (int nb = 0; nb < 8; ++nb) ob[nb * 16] = O1[nb][r] * ss4[r];
        }
    }
}

extern "C" void kernel_launch(void* const* d_in, const int* in_sizes, int n_in,
                              void* d_out, int out_size, void* d_ws, size_t ws_size,
                              hipStream_t stream) {
    (void)in_sizes; (void)n_in; (void)out_size; (void)d_ws; (void)ws_size;
    const float* q   = (const float*)d_in[0];
    const float* k   = (const float*)d_in[1];
    const float* v   = (const float*)d_in[2];
    const float* lq1 = (const float*)d_in[3];
    const float* lk1 = (const float*)d_in[4];
    const float* lq2 = (const float*)d_in[5];
    const float* lk2 = (const float*)d_in[6];
    float* out = (float*)d_out;
    // 512 blocks = 32 balanced q-tile pairs x 16 (b,h); every block = 65 tiles
    fda_kernel<<<dim3(512), dim3(256), 0, stream>>>(q, k, v, lq1, lk1, lq2, lk2, out);
}

// Round 3
// 287.877 us; speedup vs baseline: 2.4848x; 1.3560x over previous
//
#include <hip/hip_runtime.h>
#include <math.h>

// FlashDiffAttention on MI355X (gfx950). Round 3.
// Prepass: Q/K/V fp32 -> bf16 in d_ws (Q frag-linear w/ scale; K tile-major
// chunk-XOR-swizzled; V transposed [n][key] per 32-key tile).
// Main: BM=64 rows/block, BN=32. 4 waves = (rg: row-half) x (u: attn for
// QK/softmax, n-half for PV). global_load_lds double-buffered staging.
// Shared tile-max across rows+attns -> uniform alpha; per-lane deferred l.

#define S_LEN 2048
#define ROWSTR 2048
#define NEG_BIG (-3.0e38f)
#define QSCALE (1.44269504088896f * 0.0883883476483184f)
#define LAMBDA_INIT 0.783605766532f

typedef __attribute__((ext_vector_type(8))) short short8;
typedef __attribute__((ext_vector_type(4))) float f32x4;

__device__ __forceinline__ short f2bf(float f) {
    unsigned u = __builtin_bit_cast(unsigned, f);
    u += 0x7fffu + ((u >> 16) & 1u);
    return (short)(u >> 16);
}

__device__ __forceinline__ void async16(const short* g, short* l) {
    __builtin_amdgcn_global_load_lds(
        (const __attribute__((address_space(1))) unsigned int*)g,
        (__attribute__((address_space(3))) unsigned int*)l, 16, 0, 0);
}

// ---------------- prepass: one block per (bh, key-tile t) ----------------
__global__ __launch_bounds__(256)
void prep_kernel(const float* __restrict__ q, const float* __restrict__ k,
                 const float* __restrict__ v,
                 short* __restrict__ kws, short* __restrict__ vws,
                 short* __restrict__ qws) {
    const int tid = threadIdx.x;
    const int bh  = blockIdx.x >> 6;
    const int t   = blockIdx.x & 63;
    const int b   = bh >> 3;
    const int h   = bh & 7;

    // --- K and Q: thread = (attn, key, tt); reads 32 contiguous fp32 ---
    {
        const int attn = tid >> 7;
        const int key  = (tid >> 2) & 31;
        const int tt   = tid & 3;
        const int s    = t * 32 + key;
        const float* src = k + (((size_t)(b * S_LEN + s) * 16) + 2 * h + attn) * 128 + tt * 32;
        const float* qsrc = q + (((size_t)(b * S_LEN + s) * 16) + 2 * h + attn) * 128 + tt * 32;
        short* kdst = kws + (((size_t)(bh * 64 + t)) << 13) + attn * 4096 + key * 128;
        const int rowtile = s >> 4;
        const int mi      = s & 15;
        short* qdst = qws + (((size_t)(bh * 2 + attn)) << 18) + (rowtile << 11) + (mi << 3);
        #pragma unroll
        for (int i = 0; i < 4; ++i) {
            const int c = tt * 4 + i;
            float4 a0 = *(const float4*)(src + i * 8);
            float4 a1 = *(const float4*)(src + i * 8 + 4);
            short8 sv;
            sv[0]=f2bf(a0.x); sv[1]=f2bf(a0.y); sv[2]=f2bf(a0.z); sv[3]=f2bf(a0.w);
            sv[4]=f2bf(a1.x); sv[5]=f2bf(a1.y); sv[6]=f2bf(a1.z); sv[7]=f2bf(a1.w);
            *(short8*)(kdst + ((c ^ (key & 7)) << 3)) = sv;
            a0 = *(const float4*)(qsrc + i * 8);
            a1 = *(const float4*)(qsrc + i * 8 + 4);
            sv[0]=f2bf(a0.x*QSCALE); sv[1]=f2bf(a0.y*QSCALE); sv[2]=f2bf(a0.z*QSCALE); sv[3]=f2bf(a0.w*QSCALE);
            sv[4]=f2bf(a1.x*QSCALE); sv[5]=f2bf(a1.y*QSCALE); sv[6]=f2bf(a1.z*QSCALE); sv[7]=f2bf(a1.w*QSCALE);
            *(short8*)(qdst + (c << 7)) = sv;
        }
    }

    // --- V: thread = n (0..255); gathers 32 keys, writes contiguous ---
    {
        const int n = tid;
        const float* vsrc = v + (((size_t)(b * S_LEN + t * 32) * 16) + 2 * h + (n >> 7)) * 128 + (n & 127);
        short vv[32];
        #pragma unroll
        for (int key = 0; key < 32; ++key)
            vv[key] = f2bf(vsrc[(size_t)key * ROWSTR]);
        short* vdst = vws + (((size_t)(bh * 64 + t)) << 13) + n * 32;
        #pragma unroll
        for (int i = 0; i < 4; ++i)
            *(short8*)(vdst + i * 8) = *(short8*)&vv[i * 8];
    }
}

// ---------------- main kernel ----------------
__global__ __launch_bounds__(256, 2)
void fda_kernel(const short* __restrict__ kws, const short* __restrict__ vws,
                const short* __restrict__ qws,
                const float* __restrict__ lq1, const float* __restrict__ lk1,
                const float* __restrict__ lq2, const float* __restrict__ lk2,
                float* __restrict__ out) {
    __shared__ short sK[2][2][32][128];   // [buf][attn][key][d swizzled]
    __shared__ short sV[2][256][32];      // [buf][n][key]
    __shared__ short sP[2][64][40];       // [attn][row][key] (+8 pad)
    __shared__ float sM[2][2];            // [rg][u] tile max
    __shared__ float sL[2][64];           // [attn][row] final l
    __shared__ float sRed[2][2][32];      // [rg][u][row] rms partials

    const int tid  = threadIdx.x;
    const int w    = tid >> 6;
    const int lane = tid & 63;
    const int mi   = lane & 15;
    const int quad = lane >> 4;
    const int rg   = w & 1;               // row half (32 rows)
    const int u    = w >> 1;              // attn (QK) / n-half (PV)

    const int bid = blockIdx.x;
    const int bh  = bid & 15;
    const int g   = bid >> 4;
    const int qt  = (g < 16) ? (31 - g) : (g - 16);  // balanced pairs: 68/CU
    const int b   = bh >> 3;
    const int h   = bh & 7;
    const int qbase = qt * 64;
    const int nt  = 2 * qt + 2;

    // ---- lambda_full ----
    float d1 = lq1[lane] * lk1[lane] + lq1[lane + 64] * lk1[lane + 64];
    float d2 = lq2[lane] * lk2[lane] + lq2[lane + 64] * lk2[lane + 64];
    #pragma unroll
    for (int off = 32; off; off >>= 1) {
        d1 += __shfl_xor(d1, off);
        d2 += __shfl_xor(d2, off);
    }
    const float lambda_full = expf(d1) - expf(d2) + LAMBDA_INIT;

    // ---- Q fragments (attn = u), frag-linear in qws ----
    short8 qf[2][4];
    {
        const short* qb = qws + (((size_t)(bh * 2 + u)) << 18);
        #pragma unroll
        for (int m = 0; m < 2; ++m) {
            const int rowtile = qt * 4 + rg * 2 + m;
            #pragma unroll
            for (int db = 0; db < 4; ++db)
                qf[m][db] = *(const short8*)(qb + (rowtile << 11) + (((db << 2) + quad) << 7) + (mi << 3));
        }
    }

    // ---- state ----
    float mold = -1e30f;
    float l[2][4] = {{0.f,0.f,0.f,0.f},{0.f,0.f,0.f,0.f}};
    f32x4 O[2][2][8];                      // [attn][m][nb]
    #pragma unroll
    for (int a = 0; a < 2; ++a)
        #pragma unroll
        for (int m = 0; m < 2; ++m)
            #pragma unroll
            for (int nb = 0; nb < 8; ++nb)
                O[a][m][nb] = (f32x4){0.f, 0.f, 0.f, 0.f};

    const short* ktile0 = kws + (((size_t)(bh * 64)) << 13);
    const short* vtile0 = vws + (((size_t)(bh * 64)) << 13);

    // ---- stage tile 0 ----
    {
        short* dk = &sK[0][0][0][0];
        short* dv = &sV[0][0][0];
        #pragma unroll
        for (int i = 0; i < 4; ++i) {
            const int ch = (w * 4 + i) * 512;
            async16(ktile0 + ch + lane * 8, dk + ch);
            async16(vtile0 + ch + lane * 8, dv + ch);
        }
    }

    for (int t = 0; t < nt; ++t) {
        __syncthreads();                  // B1: buf[t&1] staged
        const int buf = t & 1;
        const bool act = (t <= 2 * qt + rg);

        f32x4 S[2][2];
        if (act) {
            #pragma unroll
            for (int m = 0; m < 2; ++m)
                #pragma unroll
                for (int kh = 0; kh < 2; ++kh)
                    S[m][kh] = (f32x4){0.f, 0.f, 0.f, 0.f};
            const short* kb = &sK[buf][u][0][0];
            #pragma unroll
            for (int db = 0; db < 4; ++db) {
                #pragma unroll
                for (int kh = 0; kh < 2; ++kh) {
                    const short8 kf = *(const short8*)(kb + (kh * 16 + mi) * 128 +
                                       ((((db << 2) + quad) ^ (mi & 7)) << 3));
                    S[0][kh] = __builtin_amdgcn_mfma_f32_16x16x32_bf16(qf[0][db], kf, S[0][kh], 0, 0, 0);
                    S[1][kh] = __builtin_amdgcn_mfma_f32_16x16x32_bf16(qf[1][db], kf, S[1][kh], 0, 0, 0);
                }
            }
            if (t == 2 * qt + rg) {       // diagonal tile
                const int qr0 = qbase + rg * 32;
                #pragma unroll
                for (int m = 0; m < 2; ++m)
                    #pragma unroll
                    for (int kh = 0; kh < 2; ++kh)
                        #pragma unroll
                        for (int r = 0; r < 4; ++r)
                            if (t * 32 + kh * 16 + mi > qr0 + m * 16 + quad * 4 + r)
                                S[m][kh][r] = NEG_BIG;
            }
            // wave tile-max (shared across rows; combined with other attn via sM)
            float mx = -1e30f;
            #pragma unroll
            for (int m = 0; m < 2; ++m)
                #pragma unroll
                for (int kh = 0; kh < 2; ++kh)
                    mx = fmaxf(mx, fmaxf(fmaxf(S[m][kh][0], S[m][kh][1]),
                                         fmaxf(S[m][kh][2], S[m][kh][3])));
            #pragma unroll
            for (int off = 32; off; off >>= 1)
                mx = fmaxf(mx, __shfl_xor(mx, off));
            if (lane == 0) sM[rg][u] = mx;
        }
        __syncthreads();                  // B2: sM visible

        float alpha = 1.0f;
        if (act) {
            const float mnew = fmaxf(mold, fmaxf(sM[rg][0], sM[rg][1]));
            alpha = exp2f(mold - mnew);
            mold = mnew;
            #pragma unroll
            for (int m = 0; m < 2; ++m) {
                short* pp = &sP[u][rg * 32 + m * 16 + quad * 4][mi];
                #pragma unroll
                for (int r = 0; r < 4; ++r) {
                    const float pa = exp2f(S[m][0][r] - mnew);
                    const float pb = exp2f(S[m][1][r] - mnew);
                    l[m][r] = l[m][r] * alpha + (pa + pb);
                    pp[r * 40]      = f2bf(pa);
                    pp[r * 40 + 16] = f2bf(pb);
                }
            }
        }
        __syncthreads();                  // B3: sP visible

        // prefetch next tile (flies during PV, drained at next B1)
        if (t + 1 < nt) {
            const short* kt = ktile0 + (((size_t)(t + 1)) << 13);
            const short* vt = vtile0 + (((size_t)(t + 1)) << 13);
            short* dk = &sK[(t + 1) & 1][0][0][0];
            short* dv = &sV[(t + 1) & 1][0][0];
            #pragma unroll
            for (int i = 0; i < 4; ++i) {
                const int ch = (w * 4 + i) * 512;
                async16(kt + ch + lane * 8, dk + ch);
                async16(vt + ch + lane * 8, dv + ch);
            }
        }

        if (act) {
            if (alpha != 1.0f) {
                #pragma unroll
                for (int a = 0; a < 2; ++a)
                    #pragma unroll
                    for (int m = 0; m < 2; ++m)
                        #pragma unroll
                        for (int nb = 0; nb < 8; ++nb)
                            #pragma unroll
                            for (int r = 0; r < 4; ++r)
                                O[a][m][nb][r] *= alpha;
            }
            short8 pA[2][2];
            #pragma unroll
            for (int a = 0; a < 2; ++a)
                #pragma unroll
                for (int m = 0; m < 2; ++m)
                    pA[a][m] = *(const short8*)&sP[a][rg * 32 + m * 16 + mi][quad * 8];
            #pragma unroll
            for (int nb = 0; nb < 8; ++nb) {
                const short8 bv = *(const short8*)&sV[buf][u * 128 + nb * 16 + mi][quad * 8];
                O[0][0][nb] = __builtin_amdgcn_mfma_f32_16x16x32_bf16(pA[0][0], bv, O[0][0][nb], 0, 0, 0);
                O[0][1][nb] = __builtin_amdgcn_mfma_f32_16x16x32_bf16(pA[0][1], bv, O[0][1][nb], 0, 0, 0);
                O[1][0][nb] = __builtin_amdgcn_mfma_f32_16x16x32_bf16(pA[1][0], bv, O[1][0][nb], 0, 0, 0);
                O[1][1][nb] = __builtin_amdgcn_mfma_f32_16x16x32_bf16(pA[1][1], bv, O[1][1][nb], 0, 0, 0);
            }
        }
    }

    // ---- epilogue ----
    #pragma unroll
    for (int m = 0; m < 2; ++m)
        #pragma unroll
        for (int r = 0; r < 4; ++r) {
            float s = l[m][r];
            s += __shfl_xor(s, 1); s += __shfl_xor(s, 2);
            s += __shfl_xor(s, 4); s += __shfl_xor(s, 8);
            l[m][r] = s;
        }
    if (mi == 0) {
        #pragma unroll
        for (int m = 0; m < 2; ++m)
            #pragma unroll
            for (int r = 0; r < 4; ++r)
                sL[u][rg * 32 + m * 16 + quad * 4 + r] = l[m][r];
    }
    __syncthreads();

    float ss[2][4] = {{0.f,0.f,0.f,0.f},{0.f,0.f,0.f,0.f}};
    #pragma unroll
    for (int m = 0; m < 2; ++m)
        #pragma unroll
        for (int r = 0; r < 4; ++r) {
            const int row = rg * 32 + m * 16 + quad * 4 + r;
            const float il1 = 1.0f / sL[0][row];
            const float il2 = lambda_full / sL[1][row];
            #pragma unroll
            for (int nb = 0; nb < 8; ++nb) {
                const float c = O[0][m][nb][r] * il1 - O[1][m][nb][r] * il2;
                O[0][m][nb][r] = c;
                ss[m][r] += c * c;
            }
        }
    #pragma unroll
    for (int m = 0; m < 2; ++m)
        #pragma unroll
        for (int r = 0; r < 4; ++r) {
            float s = ss[m][r];
            s += __shfl_xor(s, 1); s += __shfl_xor(s, 2);
            s += __shfl_xor(s, 4); s += __shfl_xor(s, 8);
            ss[m][r] = s;
        }
    if (mi == 0) {
        #pragma unroll
        for (int m = 0; m < 2; ++m)
            #pragma unroll
            for (int r = 0; r < 4; ++r)
                sRed[rg][u][m * 16 + quad * 4 + r] = ss[m][r];
    }
    __syncthreads();

    #pragma unroll
    for (int m = 0; m < 2; ++m)
        #pragma unroll
        for (int r = 0; r < 4; ++r) {
            const int rl  = m * 16 + quad * 4 + r;
            const float tot = ss[m][r] + sRed[rg][u ^ 1][rl];
            const float scale = rsqrtf(tot * (1.0f / 256.0f) + 1e-5f) * (1.0f - LAMBDA_INIT);
            const int gr = qbase + rg * 32 + rl;
            float* ob = out + ((size_t)(b * S_LEN + gr)) * ROWSTR + h * 256 + u * 128 + mi;
            #pragma unroll
            for (int nb = 0; nb < 8; ++nb)
                ob[nb * 16] = O[0][m][nb][r] * scale;
        }
}

extern "C" void kernel_launch(void* const* d_in, const int* in_sizes, int n_in,
                              void* d_out, int out_size, void* d_ws, size_t ws_size,
                              hipStream_t stream) {
    (void)in_sizes; (void)n_in; (void)out_size; (void)ws_size;
    const float* q   = (const float*)d_in[0];
    const float* k   = (const float*)d_in[1];
    const float* v   = (const float*)d_in[2];
    const float* lq1 = (const float*)d_in[3];
    const float* lk1 = (const float*)d_in[4];
    const float* lq2 = (const float*)d_in[5];
    const float* lk2 = (const float*)d_in[6];
    float* out = (float*)d_out;

    short* kws = (short*)d_ws;                 // 16 bh x 64 tiles x 8192
    short* vws = kws + (size_t)16 * 64 * 8192;
    short* qws = vws + (size_t)16 * 64 * 8192; // total 50.3 MB

    prep_kernel<<<dim3(1024), dim3(256), 0, stream>>>(q, k, v, kws, vws, qws);
    fda_kernel<<<dim3(512), dim3(256), 0, stream>>>(kws, vws, qws,
                                                    lq1, lk1, lq2, lk2, out);
}